// Round 5
// baseline (191.238 us; speedup 1.0000x reference)
//
#include <hip/hip_runtime.h>
#include <stdint.h>

#pragma clang fp contract(off)

#define N_ANCH 90000
#define M_TOP  1024          // selection scope; walk fast path covers M_L=512
#define M_L    512           // mask/walk fast-path scope; stop row ~330 for this input
#define NW_L   8             // mask words per row (M_L/64)
#define K_POST 300
#define CAP    2048          // candidate capacity
#define WINB   0x3D00        // hist window base: p>=~0.031
#define WINSZ  768           // window bins [0x3D00, 0x4000) — all bins >= WINB
#define MIN_SIZE (16.0f / 800.0f)
#define IOU_THR  0.7f

#define NB_D   176           // decode blocks (x512 thr; 1 anchor/thread)
#define NB_S   32            // select blocks (x1024 thr)
#define GPB    704           // uint4 key-groups per select block: ceil(22500/32)
#define G4     (N_ANCH / 4)  // 22500

// sb[] bank-conflict swizzle
#define SIDX(j) ((j) + ((j) >> 6))
#define SB_SZ   (M_L + NW_L)

// ---- workspace layout (bytes); all regions written before read; no memset ----
#define OFF_CNT   0                          // int (zeroed by decode blk0)
#define OFF_D1    64                         // int spin counter (zeroed by decode blk0)
#define OFF_D2    128                        // int last-block counter (zeroed by decode blk0)
#define OFF_HIST  192                        // u16[768*176] = 270336 -> 270528
#define OFF_ROI   270528                     // float4[90000] = 1440000 -> 1710528
#define OFF_KEYS  1710528                    // u32[90000] = 360000 -> 2070528
#define OFF_CAND  2070528                    // u64[2048] = 16384 -> 2086912
#define OFF_SBOX  2086912                    // float4[1024] = 16384 -> 2103296

// ============================================================================
// 1) decode: 176 blocks x 512, one anchor/thread (proven). Writes roi, keys,
//    transposed u16 hist hist[bin*176 + bid]; blk0 zeroes cnt/d1/d2.
// ============================================================================
__global__ void __launch_bounds__(512)
decode_kernel(const float2* __restrict__ cls,
              const float4* __restrict__ reg,
              const float4* __restrict__ anc,
              float4* __restrict__ roi,
              unsigned* __restrict__ keys,
              unsigned short* __restrict__ hist,
              int* __restrict__ cnt,
              int* __restrict__ d1,
              int* __restrict__ d2) {
    __shared__ int lh[WINSZ];
    const int tid = threadIdx.x;
    const int bid = blockIdx.x;
    for (int k = tid; k < WINSZ; k += 512) lh[k] = 0;
    if (bid == 0 && tid == 0) { cnt[0] = 0; d1[0] = 0; d2[0] = 0; }
    __syncthreads();

    const int n = bid * 512 + tid;
    if (n < N_ANCH) {
        float4 a = anc[n];
        float4 r = reg[n];
        float aw  = a.z - a.x;
        float ah  = a.w - a.y;
        float acx = (a.z + a.x) * 0.5f;
        float acy = (a.w + a.y) * 0.5f;
        float cx = r.x * aw + acx;
        float cy = r.y * ah + acy;
        float w  = expf(r.z) * aw;
        float h  = expf(r.w) * ah;
        float x1 = fminf(fmaxf(cx - w * 0.5f, 0.0f), 1.0f);
        float y1 = fminf(fmaxf(cy - h * 0.5f, 0.0f), 1.0f);
        float x2 = fminf(fmaxf(cx + w * 0.5f, 0.0f), 1.0f);
        float y2 = fminf(fmaxf(cy + h * 0.5f, 0.0f), 1.0f);
        roi[n] = make_float4(x1, y1, x2, y2);

        float2 c = cls[n];
        float m  = fmaxf(c.x, c.y);
        float e0 = expf(c.x - m);
        float e1 = expf(c.y - m);
        float p  = e1 / (e0 + e1);

        bool ok = ((x2 - x1) >= MIN_SIZE) && ((y2 - y1) >= MIN_SIZE);
        unsigned key = ok ? (__float_as_uint(p) ^ 0x80000000u) : 0u;  // monotone; invalid -> 0
        keys[n] = key;
        if (key != 0u) {
            int hb = (int)(key >> 16) - 0x8000;
            if (hb >= WINB) atomicAdd(&lh[hb - WINB], 1);
        }
    }
    __syncthreads();
    for (int k = tid; k < WINSZ; k += 512)
        hist[k * NB_D + bid] = (unsigned short)lh[k];   // count <= 512 fits u16
}

__device__ __forceinline__ unsigned long long readlane64(unsigned long long v, int sl) {
    unsigned lo = (unsigned)__builtin_amdgcn_readlane((int)(unsigned)v, sl);
    unsigned hi = (unsigned)__builtin_amdgcn_readlane((int)(unsigned)(v >> 32), sl);
    return ((unsigned long long)hi << 32) | lo;
}

// ============================================================================
// 2) select: 32 blocks x 1024.
//    A: threshold (shfl scan over transposed hist; 3 barriers)
//    B: slice compact -> cand/cnt (round-2 proven ballot code, distributed)
//    S1: 32-way spin sync (threadfence + agent atomics; 32 blocks co-resident)
//    C: rank own 64 cands (round-2 proven), scatter sbox
//    S2: last-block gate (no spin)
//    D: last block builds sb + 32KB lmask in LDS (4 words/thread)
//    E: last block runs the proven serial walk (wave 0) + writes out
// ============================================================================
__global__ void __launch_bounds__(1024)
select_kernel(const unsigned* __restrict__ keys,
              const unsigned short* __restrict__ hist,
              const float4* __restrict__ roi,
              int* cnt,
              unsigned long long* cand,
              float4* sbox,
              int* d1,
              int* d2,
              float4* __restrict__ out) {
    __shared__ __align__(16) char arena[8320 + 32768];  // C: sc[2048]+red | D/E: sb+lmask
    __shared__ int s_w[16];
    __shared__ unsigned s_thr;
    __shared__ int wcnt[16], wbase[16], s_base;
    __shared__ int s_last;
    __shared__ int s_keep[K_POST];
    __shared__ int s_kc;
    const int t = threadIdx.x;
    const int bid = blockIdx.x;
    const int lane = t & 63, wv = t >> 6;

    // ---- A: threshold. own = count in bin (767-t); incl-scan over t => suffix sums ----
    int own = 0;
    if (t < WINSZ) {
        const uint4* hp = (const uint4*)(hist + (WINSZ - 1 - t) * NB_D);
#pragma unroll
        for (int q = 0; q < NB_D / 8; ++q) {            // 22 uint4 = 176 u16, contiguous
            uint4 u = hp[q];
            own += (int)((u.x & 0xffffu) + (u.x >> 16) + (u.y & 0xffffu) + (u.y >> 16)
                       + (u.z & 0xffffu) + (u.z >> 16) + (u.w & 0xffffu) + (u.w >> 16));
        }
    }
    int x = own;
#pragma unroll
    for (int d = 1; d < 64; d <<= 1) { int y = __shfl_up(x, d); if (lane >= d) x += y; }
    if (lane == 63) s_w[wv] = x;
    __syncthreads();
    int incl = x;
#pragma unroll
    for (int q = 0; q < 16; ++q) if (q < wv) incl += s_w[q];
    if (t < WINSZ && incl >= M_TOP && (incl - own) < M_TOP)
        s_thr = ((unsigned)(0x8000 + WINB + (WINSZ - 1 - t))) << 16;  // unique crossing
    if (t == 1023 && incl < M_TOP)
        s_thr = 0x80000000u;                            // window insufficient: all valid
    __syncthreads();
    const unsigned thr = s_thr;

    // ---- B: compact own slice (1 uint4 group per thread) ----
    unsigned pm = 0;
    uint4 kv = make_uint4(0u, 0u, 0u, 0u);
    const int g = bid * GPB + t;
    if (t < GPB && g < G4) {
        kv = ((const uint4*)keys)[g];
        pm = (kv.x >= thr ? 1u : 0u) | (kv.y >= thr ? 2u : 0u)
           | (kv.z >= thr ? 4u : 0u) | (kv.w >= thr ? 8u : 0u);
    }
    unsigned long long b0 = __ballot((pm & 1u) != 0u);
    unsigned long long b1 = __ballot((pm & 2u) != 0u);
    unsigned long long b2 = __ballot((pm & 4u) != 0u);
    unsigned long long b3 = __ballot((pm & 8u) != 0u);
    if (lane == 0)
        wcnt[wv] = __popcll(b0) + __popcll(b1) + __popcll(b2) + __popcll(b3);
    __syncthreads();
    if (t == 0) {
        int s = 0;
#pragma unroll
        for (int q = 0; q < 16; ++q) { wbase[q] = s; s += wcnt[q]; }
        s_base = s ? atomicAdd(cnt, s) : 0;             // one global atomic per block
    }
    __syncthreads();
    if (pm) {
        unsigned long long lt = (lane == 0) ? 0ull : ((1ull << lane) - 1ull);
        int pos = s_base + wbase[wv]
                + __popcll(b0 & lt) + __popcll(b1 & lt) + __popcll(b2 & lt) + __popcll(b3 & lt);
        int n0 = g * 4;
        if (pm & 1u) { if (pos < CAP) cand[pos] = ((unsigned long long)kv.x << 32) | (unsigned)(~(unsigned)n0);       ++pos; }
        if (pm & 2u) { if (pos < CAP) cand[pos] = ((unsigned long long)kv.y << 32) | (unsigned)(~(unsigned)(n0 + 1)); ++pos; }
        if (pm & 4u) { if (pos < CAP) cand[pos] = ((unsigned long long)kv.z << 32) | (unsigned)(~(unsigned)(n0 + 2)); ++pos; }
        if (pm & 8u) { if (pos < CAP) cand[pos] = ((unsigned long long)kv.w << 32) | (unsigned)(~(unsigned)(n0 + 3)); ++pos; }
    }

    // ---- S1: 32-way spin sync (all blocks need complete cand for rank) ----
    __syncthreads();                                    // drain block's stores
    __threadfence();                                    // agent release
    if (t == 0) {
        __hip_atomic_fetch_add(d1, 1, __ATOMIC_ACQ_REL, __HIP_MEMORY_SCOPE_AGENT);
        while (__hip_atomic_load(d1, __ATOMIC_ACQUIRE, __HIP_MEMORY_SCOPE_AGENT) < NB_S)
            __builtin_amdgcn_s_sleep(2);
    }
    __syncthreads();
    __threadfence();                                    // agent acquire for all threads

    // ---- C: rank own 64 cands against full array (round-2 proven) ----
    unsigned long long* sc = (unsigned long long*)arena;        // [2048] 16 KB
    int* red = (int*)(arena + CAP * 8);                         // [1024] 4 KB
    int c = __hip_atomic_load(cnt, __ATOMIC_RELAXED, __HIP_MEMORY_SCOPE_AGENT);
    if (c > CAP) c = CAP;
    for (int k = t; k < CAP; k += 1024)
        sc[k] = (k < c) ? __hip_atomic_load(&cand[k], __ATOMIC_RELAXED, __HIP_MEMORY_SCOPE_AGENT)
                        : 0ULL;
    __syncthreads();
    {
        int e = t & 63, slice = t >> 6;
        int i = bid * 64 + e;
        unsigned long long v = (i < c) ? sc[i] : 0ULL;
        int cg = 0;
        if (i < c) {
            int kb = slice * (CAP / 16), ke = kb + CAP / 16;
            if (ke > c) ke = c;
#pragma unroll 4
            for (int k = kb; k < ke; ++k) cg += (sc[k] > v) ? 1 : 0;
        }
        red[t] = cg;
        __syncthreads();
        if (slice == 0 && i < c) {
            int rank = 0;
#pragma unroll
            for (int q = 0; q < 16; ++q) rank += red[e + 64 * q];
            if (rank < M_TOP) sbox[rank] = roi[~(unsigned)v];
        }
    }

    // ---- S2: last-block gate (only the walker continues; no spin) ----
    __syncthreads();
    __threadfence();
    if (t == 0) {
        int old = __hip_atomic_fetch_add(d2, 1, __ATOMIC_ACQ_REL, __HIP_MEMORY_SCOPE_AGENT);
        s_last = (old == NB_S - 1);
    }
    __syncthreads();
    if (!s_last) return;
    __threadfence();                                    // acquire: other blocks' sbox writes

    // ---- D: build sb (swizzled) + 32 KB lmask in LDS ----
    float4* sb = (float4*)arena;                        // [520] 8320 B (sc dead)
    unsigned long long* lmask = (unsigned long long*)(arena + 8320);  // [4096] 32 KB
    if (t < M_L)
        sb[SIDX(t)] = (t < c) ? sbox[t] : make_float4(0.f, 0.f, 0.f, 0.f);
    __syncthreads();
#pragma unroll
    for (int q = 0; q < 4; ++q) {
        int wid = q * 1024 + t;                         // [0, 4096)
        int i = wid >> 3;
        int w = wid & 7;
        unsigned long long bits = 0;
        int j0 = w << 6;
        if (j0 + 63 > i) {                              // skip words fully below diagonal
            float4 bi = sb[SIDX(i)];
            float ai = (bi.z - bi.x) * (bi.w - bi.y);
            for (int b = 0; b < 64; ++b) {
                int j = j0 + b;
                if (j > i) {
                    float4 bj = sb[SIDX(j)];
                    float xx1 = fmaxf(bi.x, bj.x);
                    float yy1 = fmaxf(bi.y, bj.y);
                    float xx2 = fminf(bi.z, bj.z);
                    float yy2 = fminf(bi.w, bj.w);
                    float ww = fmaxf(xx2 - xx1, 0.0f);
                    float hh = fmaxf(yy2 - yy1, 0.0f);
                    float inter = ww * hh;
                    float aj = (bj.z - bj.x) * (bj.w - bj.y);
                    float uni = ai + aj - inter;
                    float iou = inter / fmaxf(uni, 1e-12f);
                    if (iou > IOU_THR) bits |= 1ull << b;
                }
            }
        }
        lmask[wid] = bits;
    }
    __syncthreads();

    // ---- E: serial greedy walk, wave 0 (proven code; source = lmask) ----
    if (t < 64) {
        int wl = t;
        int c_eff = c;
        if (c_eff > M_TOP) c_eff = M_TOP;

        unsigned long long diag[NW_L];
#pragma unroll
        for (int cc = 0; cc < NW_L; ++cc)
            diag[cc] = lmask[(((cc << 6) | wl) << 3) + cc];

        unsigned long long remw = 0;
        int w = wl & 7;
        int kgrp = wl >> 3;
        int kc = 0;
        bool stop = false;
#pragma unroll
        for (int cc = 0; cc < NW_L; ++cc) {
            int base = cc << 6;
            unsigned long long valid =
                (c_eff >= base + 64) ? ~0ull
              : ((c_eff <= base) ? 0ull : ((1ull << (c_eff - base)) - 1ull));
            unsigned long long live = valid & ~readlane64(remw, cc);
            unsigned long long keptbits = 0;
            while (live) {
                int b = __ffsll((unsigned long long)live) - 1;
                keptbits |= 1ull << b;
                if (wl == 0) s_keep[kc] = base + b;
                ++kc;
                if (kc >= K_POST) { stop = true; break; }
                live &= ~readlane64(diag[cc], b);
                live &= ~(1ull << b);
            }
            if (stop) break;
            if (cc == NW_L - 1) break;
            if (keptbits) {
                int nk = __popcll(keptbits);
                int mypos = 0;
                if (wl < nk) {
                    unsigned long long tmp = keptbits;
                    for (int p = 0; p < wl; ++p) tmp &= tmp - 1;
                    mypos = base + (__ffsll((unsigned long long)tmp) - 1);
                }
                unsigned long long acc = 0;
#pragma unroll
                for (int r = 0; r < 8; ++r) {
                    int kg = (r << 3) | kgrp;
                    int row = __shfl(mypos, kg);
                    unsigned long long vv = (kg < nk) ? lmask[(row << 3) + w] : 0ull;
                    acc |= vv;
                }
                acc |= __shfl_xor(acc, 8);
                acc |= __shfl_xor(acc, 16);
                acc |= __shfl_xor(acc, 32);
                remw |= acc;
            }
        }
        // cold fallback: rows [M_L, c_eff) vs kept set (correctness only)
        if (!stop) {
            for (int i = M_L; i < c_eff && kc < K_POST; ++i) {
                float4 bi = sbox[i];
                float ai = (bi.z - bi.x) * (bi.w - bi.y);
                bool any = false;
                for (int k = wl; k < kc; k += 64) {
                    float4 bk = sbox[s_keep[k]];
                    float xx1 = fmaxf(bi.x, bk.x);
                    float yy1 = fmaxf(bi.y, bk.y);
                    float xx2 = fminf(bi.z, bk.z);
                    float yy2 = fminf(bi.w, bk.w);
                    float ww = fmaxf(xx2 - xx1, 0.0f);
                    float hh = fmaxf(yy2 - yy1, 0.0f);
                    float inter = ww * hh;
                    float ak = (bk.z - bk.x) * (bk.w - bk.y);
                    float uni = ai + ak - inter;
                    if (inter / fmaxf(uni, 1e-12f) > IOU_THR) any = true;
                }
                if (__ballot(any) == 0ull) {
                    if (wl == 0) s_keep[kc] = i;
                    ++kc;
                }
            }
        }
        if (wl == 0) s_kc = kc;
    }
    __syncthreads();
    int kcf = s_kc;
    for (int j = t; j < K_POST; j += 1024)
        out[j] = (j < kcf) ? sbox[s_keep[j]] : make_float4(0.f, 0.f, 0.f, 0.f);
}

extern "C" void kernel_launch(void* const* d_in, const int* in_sizes, int n_in,
                              void* d_out, int out_size, void* d_ws, size_t ws_size,
                              hipStream_t stream) {
    const float2* cls = (const float2*)d_in[0];   // (1,100,100,18) fp32 -> logit pairs
    const float4* reg = (const float4*)d_in[1];   // (1,90000,4)
    const float4* anc = (const float4*)d_in[2];   // (90000,4)
    float4* out = (float4*)d_out;                 // 300 x 4 fp32

    char* ws = (char*)d_ws;
    int*                cnt  = (int*)(ws + OFF_CNT);
    int*                d1   = (int*)(ws + OFF_D1);
    int*                d2   = (int*)(ws + OFF_D2);
    unsigned short*     hist = (unsigned short*)(ws + OFF_HIST);
    float4*             roi  = (float4*)(ws + OFF_ROI);
    unsigned*           keys = (unsigned*)(ws + OFF_KEYS);
    unsigned long long* cand = (unsigned long long*)(ws + OFF_CAND);
    float4*             sbox = (float4*)(ws + OFF_SBOX);

    decode_kernel<<<NB_D, 512, 0, stream>>>(cls, reg, anc, roi, keys, hist, cnt, d1, d2);
    select_kernel<<<NB_S, 1024, 0, stream>>>(keys, hist, roi, cnt, cand, sbox, d1, d2, out);
}

// Round 6
// 171.332 us; speedup vs baseline: 1.1162x; 1.1162x over previous
//
#include <hip/hip_runtime.h>
#include <stdint.h>

#pragma clang fp contract(off)

#define N_ANCH 90000
#define M_TOP  1024          // selection scope; walk fast path covers M_L=512
#define M_L    512           // mask/walk fast-path scope; stop row ~330 for this input
#define NW_L   8             // mask words per row (M_L/64)
#define K_POST 300
#define CAP    2048          // candidate capacity
#define WINB   0x3D00        // hist window base: p>=~0.031
#define WINSZ  768           // window bins [0x3D00, 0x4000) — all bins >= WINB
#define MIN_SIZE (16.0f / 800.0f)
#define IOU_THR  0.7f

#define NB_D   176           // decode blocks (x512 thr; 1 anchor/thread)
#define NB_C   32            // compact blocks (x1024 thr)
#define GPB    704           // uint4 key-groups per compact block: ceil(22500/32)
#define G4     (N_ANCH / 4)  // 22500

// sb[] bank-conflict swizzle
#define SIDX(j) ((j) + ((j) >> 6))
#define SB_SZ   (M_L + NW_L)

// ---- workspace layout (bytes); all regions written before read; no memset ----
#define OFF_CNT   0                          // int (zeroed by decode blk0)
#define OFF_HIST  64                         // u16[768*176] = 270336 -> 270400
#define OFF_ROI   270400                     // float4[90000] = 1440000 -> 1710400
#define OFF_KEYS  1710400                    // u32[90000] = 360000 -> 2070400
#define OFF_CAND  2070400                    // u64[2048] = 16384 -> 2086784
#define OFF_SBOX  2086784                    // float4[1024] = 16384 -> 2103168

// ============================================================================
// 1) decode: 176 blocks x 512, one anchor/thread (proven R5). Writes roi,
//    keys, transposed u16 hist hist[bin*176 + bid]; blk0 zeroes cnt.
// ============================================================================
__global__ void __launch_bounds__(512)
decode_kernel(const float2* __restrict__ cls,
              const float4* __restrict__ reg,
              const float4* __restrict__ anc,
              float4* __restrict__ roi,
              unsigned* __restrict__ keys,
              unsigned short* __restrict__ hist,
              int* __restrict__ cnt) {
    __shared__ int lh[WINSZ];
    const int tid = threadIdx.x;
    const int bid = blockIdx.x;
    for (int k = tid; k < WINSZ; k += 512) lh[k] = 0;
    if (bid == 0 && tid == 0) cnt[0] = 0;
    __syncthreads();

    const int n = bid * 512 + tid;
    if (n < N_ANCH) {
        float4 a = anc[n];
        float4 r = reg[n];
        float aw  = a.z - a.x;
        float ah  = a.w - a.y;
        float acx = (a.z + a.x) * 0.5f;
        float acy = (a.w + a.y) * 0.5f;
        float cx = r.x * aw + acx;
        float cy = r.y * ah + acy;
        float w  = expf(r.z) * aw;
        float h  = expf(r.w) * ah;
        float x1 = fminf(fmaxf(cx - w * 0.5f, 0.0f), 1.0f);
        float y1 = fminf(fmaxf(cy - h * 0.5f, 0.0f), 1.0f);
        float x2 = fminf(fmaxf(cx + w * 0.5f, 0.0f), 1.0f);
        float y2 = fminf(fmaxf(cy + h * 0.5f, 0.0f), 1.0f);
        roi[n] = make_float4(x1, y1, x2, y2);

        float2 c = cls[n];
        float m  = fmaxf(c.x, c.y);
        float e0 = expf(c.x - m);
        float e1 = expf(c.y - m);
        float p  = e1 / (e0 + e1);

        bool ok = ((x2 - x1) >= MIN_SIZE) && ((y2 - y1) >= MIN_SIZE);
        unsigned key = ok ? (__float_as_uint(p) ^ 0x80000000u) : 0u;  // monotone; invalid -> 0
        keys[n] = key;
        if (key != 0u) {
            int hb = (int)(key >> 16) - 0x8000;
            if (hb >= WINB) atomicAdd(&lh[hb - WINB], 1);
        }
    }
    __syncthreads();
    for (int k = tid; k < WINSZ; k += 512)
        hist[k * NB_D + bid] = (unsigned short)lh[k];   // count <= 512 fits u16
}

// ============================================================================
// 2) compact: 32 blocks x 1024. Shfl-scan threshold (3 barriers, proven R5)
//    + slice compact via ballot + one global atomicAdd per block (proven
//    R2/R5). cand order arbitrary — rank is value-based.
// ============================================================================
__global__ void __launch_bounds__(1024)
compact_kernel(const unsigned* __restrict__ keys,
               const unsigned short* __restrict__ hist,
               int* __restrict__ cnt,
               unsigned long long* __restrict__ cand) {
    __shared__ int s_w[16];
    __shared__ unsigned s_thr;
    __shared__ int wcnt[16], wbase[16], s_base;
    const int t = threadIdx.x;
    const int bid = blockIdx.x;
    const int lane = t & 63, wv = t >> 6;

    // ---- A: threshold. own = count in bin (767-t); incl-scan => suffix sums ----
    int own = 0;
    if (t < WINSZ) {
        const uint4* hp = (const uint4*)(hist + (WINSZ - 1 - t) * NB_D);
#pragma unroll
        for (int q = 0; q < NB_D / 8; ++q) {            // 22 uint4 = 176 u16, contiguous
            uint4 u = hp[q];
            own += (int)((u.x & 0xffffu) + (u.x >> 16) + (u.y & 0xffffu) + (u.y >> 16)
                       + (u.z & 0xffffu) + (u.z >> 16) + (u.w & 0xffffu) + (u.w >> 16));
        }
    }
    int x = own;
#pragma unroll
    for (int d = 1; d < 64; d <<= 1) { int y = __shfl_up(x, d); if (lane >= d) x += y; }
    if (lane == 63) s_w[wv] = x;
    __syncthreads();
    int incl = x;
#pragma unroll
    for (int q = 0; q < 16; ++q) if (q < wv) incl += s_w[q];
    if (t < WINSZ && incl >= M_TOP && (incl - own) < M_TOP)
        s_thr = ((unsigned)(0x8000 + WINB + (WINSZ - 1 - t))) << 16;  // unique crossing
    if (t == 1023 && incl < M_TOP)
        s_thr = 0x80000000u;                            // window insufficient: all valid
    __syncthreads();
    const unsigned thr = s_thr;

    // ---- B: compact own slice (1 uint4 group per thread) ----
    unsigned pm = 0;
    uint4 kv = make_uint4(0u, 0u, 0u, 0u);
    const int g = bid * GPB + t;
    if (t < GPB && g < G4) {
        kv = ((const uint4*)keys)[g];
        pm = (kv.x >= thr ? 1u : 0u) | (kv.y >= thr ? 2u : 0u)
           | (kv.z >= thr ? 4u : 0u) | (kv.w >= thr ? 8u : 0u);
    }
    unsigned long long b0 = __ballot((pm & 1u) != 0u);
    unsigned long long b1 = __ballot((pm & 2u) != 0u);
    unsigned long long b2 = __ballot((pm & 4u) != 0u);
    unsigned long long b3 = __ballot((pm & 8u) != 0u);
    if (lane == 0)
        wcnt[wv] = __popcll(b0) + __popcll(b1) + __popcll(b2) + __popcll(b3);
    __syncthreads();
    if (t == 0) {
        int s = 0;
#pragma unroll
        for (int q = 0; q < 16; ++q) { wbase[q] = s; s += wcnt[q]; }
        s_base = s ? atomicAdd(cnt, s) : 0;             // one global atomic per block
    }
    __syncthreads();
    if (pm) {
        unsigned long long lt = (lane == 0) ? 0ull : ((1ull << lane) - 1ull);
        int pos = s_base + wbase[wv]
                + __popcll(b0 & lt) + __popcll(b1 & lt) + __popcll(b2 & lt) + __popcll(b3 & lt);
        int n0 = g * 4;
        if (pm & 1u) { if (pos < CAP) cand[pos] = ((unsigned long long)kv.x << 32) | (unsigned)(~(unsigned)n0);       ++pos; }
        if (pm & 2u) { if (pos < CAP) cand[pos] = ((unsigned long long)kv.y << 32) | (unsigned)(~(unsigned)(n0 + 1)); ++pos; }
        if (pm & 4u) { if (pos < CAP) cand[pos] = ((unsigned long long)kv.z << 32) | (unsigned)(~(unsigned)(n0 + 2)); ++pos; }
        if (pm & 8u) { if (pos < CAP) cand[pos] = ((unsigned long long)kv.w << 32) | (unsigned)(~(unsigned)(n0 + 3)); ++pos; }
    }
}

// ============================================================================
// 3) rank select: rank(i) = #{j : cand[j] > cand[i]} (u64 unique) -> scatter
//    (R2 verbatim, proven)
// ============================================================================
__global__ void __launch_bounds__(1024)
rank_select_kernel(const unsigned long long* __restrict__ cand,
                   const int* __restrict__ cnt,
                   const float4* __restrict__ roi,
                   float4* __restrict__ sbox) {
    __shared__ unsigned long long s[CAP];    // 16 KB
    __shared__ int red[1024];
    int tid = threadIdx.x;
    int c = cnt[0];
    if (c > CAP) c = CAP;
    for (int k = tid; k < CAP; k += 1024) s[k] = (k < c) ? cand[k] : 0ULL;
    __syncthreads();
    int e = tid & 63;
    int slice = tid >> 6;                    // 0..15
    int i = blockIdx.x * 64 + e;
    unsigned long long v = (i < c) ? s[i] : 0ULL;
    int cnt_gt = 0;
    if (i < c) {
        int kbeg = slice * (CAP / 16);
        int kend = kbeg + (CAP / 16);
        if (kend > c) kend = c;
#pragma unroll 4
        for (int k = kbeg; k < kend; ++k)
            cnt_gt += (s[k] > v) ? 1 : 0;
    }
    red[tid] = cnt_gt;
    __syncthreads();
    if (slice == 0 && i < c) {
        int rank = 0;
#pragma unroll
        for (int q = 0; q < 16; ++q) rank += red[e + 64 * q];
        if (rank < M_TOP) {
            unsigned idx = ~((unsigned)v);
            sbox[rank] = roi[idx];
        }
    }
}

__device__ __forceinline__ unsigned long long readlane64(unsigned long long v, int sl) {
    unsigned lo = (unsigned)__builtin_amdgcn_readlane((int)(unsigned)v, sl);
    unsigned hi = (unsigned)__builtin_amdgcn_readlane((int)(unsigned)(v >> 32), sl);
    return ((unsigned long long)hi << 32) | lo;
}

// ============================================================================
// 4) maskwalk: ONE block x 1024. Build sb (swizzled) + 32 KB lmask in LDS
//    (R5 phase D, proven; 256 IoUs/thread), then the proven serial walk on
//    wave 0 (R5 phase E) and the output write. No global mask array.
// ============================================================================
__global__ void __launch_bounds__(1024)
maskwalk_kernel(const float4* __restrict__ sbox,
                const int* __restrict__ cnt,
                float4* __restrict__ out) {
    __shared__ float4 sb[SB_SZ];                        // 8.3 KB
    __shared__ unsigned long long lmask[M_L * NW_L];    // 32 KB
    __shared__ int s_keep[K_POST];
    __shared__ int s_kc;
    const int t = threadIdx.x;

    int c = cnt[0];
    if (c > CAP) c = CAP;

    if (t < M_L)
        sb[SIDX(t)] = (t < c) ? sbox[t] : make_float4(0.f, 0.f, 0.f, 0.f);
    __syncthreads();

    // ---- mask build: 4096 words, 4 per thread ----
#pragma unroll
    for (int q = 0; q < 4; ++q) {
        int wid = q * 1024 + t;                         // [0, 4096)
        int i = wid >> 3;
        int w = wid & 7;
        unsigned long long bits = 0;
        int j0 = w << 6;
        if (j0 + 63 > i) {                              // skip words fully below diagonal
            float4 bi = sb[SIDX(i)];
            float ai = (bi.z - bi.x) * (bi.w - bi.y);
            for (int b = 0; b < 64; ++b) {
                int j = j0 + b;
                if (j > i) {
                    float4 bj = sb[SIDX(j)];
                    float xx1 = fmaxf(bi.x, bj.x);
                    float yy1 = fmaxf(bi.y, bj.y);
                    float xx2 = fminf(bi.z, bj.z);
                    float yy2 = fminf(bi.w, bj.w);
                    float ww = fmaxf(xx2 - xx1, 0.0f);
                    float hh = fmaxf(yy2 - yy1, 0.0f);
                    float inter = ww * hh;
                    float aj = (bj.z - bj.x) * (bj.w - bj.y);
                    float uni = ai + aj - inter;
                    float iou = inter / fmaxf(uni, 1e-12f);
                    if (iou > IOU_THR) bits |= 1ull << b;
                }
            }
        }
        lmask[wid] = bits;
    }
    __syncthreads();

    // ---- serial greedy walk, wave 0 (proven) ----
    if (t < 64) {
        int wl = t;
        int c_eff = c;
        if (c_eff > M_TOP) c_eff = M_TOP;

        unsigned long long diag[NW_L];
#pragma unroll
        for (int cc = 0; cc < NW_L; ++cc)
            diag[cc] = lmask[(((cc << 6) | wl) << 3) + cc];

        unsigned long long remw = 0;                    // lane holds remv word (lane&7)
        int w = wl & 7;
        int kgrp = wl >> 3;
        int kc = 0;                                     // uniform
        bool stop = false;
#pragma unroll
        for (int cc = 0; cc < NW_L; ++cc) {
            int base = cc << 6;
            unsigned long long valid =
                (c_eff >= base + 64) ? ~0ull
              : ((c_eff <= base) ? 0ull : ((1ull << (c_eff - base)) - 1ull));
            unsigned long long live = valid & ~readlane64(remw, cc);
            unsigned long long keptbits = 0;
            while (live) {
                int b = __ffsll((unsigned long long)live) - 1;
                keptbits |= 1ull << b;
                if (wl == 0) s_keep[kc] = base + b;
                ++kc;
                if (kc >= K_POST) { stop = true; break; }
                live &= ~readlane64(diag[cc], b);
                live &= ~(1ull << b);
            }
            if (stop) break;
            if (cc == NW_L - 1) break;
            if (keptbits) {
                int nk = __popcll(keptbits);
                int mypos = 0;
                if (wl < nk) {
                    unsigned long long tmp = keptbits;
                    for (int p = 0; p < wl; ++p) tmp &= tmp - 1;
                    mypos = base + (__ffsll((unsigned long long)tmp) - 1);
                }
                unsigned long long acc = 0;
#pragma unroll
                for (int r = 0; r < 8; ++r) {           // covers up to 64 kept rows/chunk
                    int kg = (r << 3) | kgrp;
                    int row = __shfl(mypos, kg);
                    unsigned long long vv = (kg < nk) ? lmask[(row << 3) + w] : 0ull;
                    acc |= vv;
                }
                acc |= __shfl_xor(acc, 8);
                acc |= __shfl_xor(acc, 16);
                acc |= __shfl_xor(acc, 32);
                remw |= acc;
            }
        }
        // cold fallback: rows [M_L, c_eff) vs kept set (correctness only)
        if (!stop) {
            for (int i = M_L; i < c_eff && kc < K_POST; ++i) {
                float4 bi = sbox[i];
                float ai = (bi.z - bi.x) * (bi.w - bi.y);
                bool any = false;
                for (int k = wl; k < kc; k += 64) {
                    float4 bk = sbox[s_keep[k]];
                    float xx1 = fmaxf(bi.x, bk.x);
                    float yy1 = fmaxf(bi.y, bk.y);
                    float xx2 = fminf(bi.z, bk.z);
                    float yy2 = fminf(bi.w, bk.w);
                    float ww = fmaxf(xx2 - xx1, 0.0f);
                    float hh = fmaxf(yy2 - yy1, 0.0f);
                    float inter = ww * hh;
                    float ak = (bk.z - bk.x) * (bk.w - bk.y);
                    float uni = ai + ak - inter;
                    if (inter / fmaxf(uni, 1e-12f) > IOU_THR) any = true;
                }
                if (__ballot(any) == 0ull) {
                    if (wl == 0) s_keep[kc] = i;
                    ++kc;
                }
            }
        }
        if (wl == 0) s_kc = kc;
    }
    __syncthreads();
    int kcf = s_kc;
    for (int j = t; j < K_POST; j += 1024)
        out[j] = (j < kcf) ? sbox[s_keep[j]] : make_float4(0.f, 0.f, 0.f, 0.f);
}

extern "C" void kernel_launch(void* const* d_in, const int* in_sizes, int n_in,
                              void* d_out, int out_size, void* d_ws, size_t ws_size,
                              hipStream_t stream) {
    const float2* cls = (const float2*)d_in[0];   // (1,100,100,18) fp32 -> logit pairs
    const float4* reg = (const float4*)d_in[1];   // (1,90000,4)
    const float4* anc = (const float4*)d_in[2];   // (90000,4)
    float4* out = (float4*)d_out;                 // 300 x 4 fp32

    char* ws = (char*)d_ws;
    int*                cnt  = (int*)(ws + OFF_CNT);
    unsigned short*     hist = (unsigned short*)(ws + OFF_HIST);
    float4*             roi  = (float4*)(ws + OFF_ROI);
    unsigned*           keys = (unsigned*)(ws + OFF_KEYS);
    unsigned long long* cand = (unsigned long long*)(ws + OFF_CAND);
    float4*             sbox = (float4*)(ws + OFF_SBOX);

    decode_kernel<<<NB_D, 512, 0, stream>>>(cls, reg, anc, roi, keys, hist, cnt);
    compact_kernel<<<NB_C, 1024, 0, stream>>>(keys, hist, cnt, cand);
    rank_select_kernel<<<CAP / 64, 1024, 0, stream>>>(cand, cnt, roi, sbox);
    maskwalk_kernel<<<1, 1024, 0, stream>>>(sbox, cnt, out);
}

// Round 7
// 116.672 us; speedup vs baseline: 1.6391x; 1.4685x over previous
//
#include <hip/hip_runtime.h>
#include <stdint.h>

#pragma clang fp contract(off)

#define N_ANCH 90000
#define M_TOP  1024          // selection scope; walk fast path covers M_L=512
#define M_L    512           // mask/walk fast-path scope; stop row ~330 for this input
#define NW_L   8             // mask words per row (M_L/64)
#define K_POST 300
#define CAP    2048          // candidate capacity
#define WINB   0x3D00        // hist window base: p>=~0.031
#define WINSZ  768           // window bins [0x3D00, 0x4000) — all bins >= WINB
#define MIN_SIZE (16.0f / 800.0f)
#define IOU_THR  0.7f

#define NB_D   176           // decode blocks (x512 thr; 1 anchor/thread)
#define NB_C   32            // compact blocks (x1024 thr)
#define GPB    704           // uint4 key-groups per compact block: ceil(22500/32)
#define G4     (N_ANCH / 4)  // 22500

// sb[] bank-conflict swizzle
#define SIDX(j) ((j) + ((j) >> 6))
#define SB_SZ   (M_L + NW_L)

// ---- workspace layout (bytes); all regions written before read; no memset ----
#define OFF_CNT   0                          // int (zeroed by decode blk0)
#define OFF_HIST  64                         // u16[768*176] = 270336 -> 270400
#define OFF_ROI   270400                     // float4[90000] = 1440000 -> 1710400
#define OFF_KEYS  1710400                    // u32[90000] = 360000 -> 2070400
#define OFF_CAND  2070400                    // u64[2048] = 16384 -> 2086784
#define OFF_SBOX  2086784                    // float4[1024] = 16384 -> 2103168
#define OFF_MASK  2103168                    // u64[4096] = 32768 -> 2135936

// ============================================================================
// 1) decode: 176 blocks x 512, one anchor/thread (proven). Writes roi, keys,
//    transposed u16 hist hist[bin*176 + bid]; blk0 zeroes cnt.
// ============================================================================
__global__ void __launch_bounds__(512)
decode_kernel(const float2* __restrict__ cls,
              const float4* __restrict__ reg,
              const float4* __restrict__ anc,
              float4* __restrict__ roi,
              unsigned* __restrict__ keys,
              unsigned short* __restrict__ hist,
              int* __restrict__ cnt) {
    __shared__ int lh[WINSZ];
    const int tid = threadIdx.x;
    const int bid = blockIdx.x;
    for (int k = tid; k < WINSZ; k += 512) lh[k] = 0;
    if (bid == 0 && tid == 0) cnt[0] = 0;
    __syncthreads();

    const int n = bid * 512 + tid;
    if (n < N_ANCH) {
        float4 a = anc[n];
        float4 r = reg[n];
        float aw  = a.z - a.x;
        float ah  = a.w - a.y;
        float acx = (a.z + a.x) * 0.5f;
        float acy = (a.w + a.y) * 0.5f;
        float cx = r.x * aw + acx;
        float cy = r.y * ah + acy;
        float w  = expf(r.z) * aw;
        float h  = expf(r.w) * ah;
        float x1 = fminf(fmaxf(cx - w * 0.5f, 0.0f), 1.0f);
        float y1 = fminf(fmaxf(cy - h * 0.5f, 0.0f), 1.0f);
        float x2 = fminf(fmaxf(cx + w * 0.5f, 0.0f), 1.0f);
        float y2 = fminf(fmaxf(cy + h * 0.5f, 0.0f), 1.0f);
        roi[n] = make_float4(x1, y1, x2, y2);

        float2 c = cls[n];
        float m  = fmaxf(c.x, c.y);
        float e0 = expf(c.x - m);
        float e1 = expf(c.y - m);
        float p  = e1 / (e0 + e1);

        bool ok = ((x2 - x1) >= MIN_SIZE) && ((y2 - y1) >= MIN_SIZE);
        unsigned key = ok ? (__float_as_uint(p) ^ 0x80000000u) : 0u;  // monotone; invalid -> 0
        keys[n] = key;
        if (key != 0u) {
            int hb = (int)(key >> 16) - 0x8000;
            if (hb >= WINB) atomicAdd(&lh[hb - WINB], 1);
        }
    }
    __syncthreads();
    for (int k = tid; k < WINSZ; k += 512)
        hist[k * NB_D + bid] = (unsigned short)lh[k];   // count <= 512 fits u16
}

// ============================================================================
// 2) compact: 32 blocks x 1024 (proven R6): shfl-scan threshold + slice
//    compact via ballot + one global atomicAdd per block.
// ============================================================================
__global__ void __launch_bounds__(1024)
compact_kernel(const unsigned* __restrict__ keys,
               const unsigned short* __restrict__ hist,
               int* __restrict__ cnt,
               unsigned long long* __restrict__ cand) {
    __shared__ int s_w[16];
    __shared__ unsigned s_thr;
    __shared__ int wcnt[16], wbase[16], s_base;
    const int t = threadIdx.x;
    const int bid = blockIdx.x;
    const int lane = t & 63, wv = t >> 6;

    int own = 0;
    if (t < WINSZ) {
        const uint4* hp = (const uint4*)(hist + (WINSZ - 1 - t) * NB_D);
#pragma unroll
        for (int q = 0; q < NB_D / 8; ++q) {
            uint4 u = hp[q];
            own += (int)((u.x & 0xffffu) + (u.x >> 16) + (u.y & 0xffffu) + (u.y >> 16)
                       + (u.z & 0xffffu) + (u.z >> 16) + (u.w & 0xffffu) + (u.w >> 16));
        }
    }
    int x = own;
#pragma unroll
    for (int d = 1; d < 64; d <<= 1) { int y = __shfl_up(x, d); if (lane >= d) x += y; }
    if (lane == 63) s_w[wv] = x;
    __syncthreads();
    int incl = x;
#pragma unroll
    for (int q = 0; q < 16; ++q) if (q < wv) incl += s_w[q];
    if (t < WINSZ && incl >= M_TOP && (incl - own) < M_TOP)
        s_thr = ((unsigned)(0x8000 + WINB + (WINSZ - 1 - t))) << 16;
    if (t == 1023 && incl < M_TOP)
        s_thr = 0x80000000u;
    __syncthreads();
    const unsigned thr = s_thr;

    unsigned pm = 0;
    uint4 kv = make_uint4(0u, 0u, 0u, 0u);
    const int g = bid * GPB + t;
    if (t < GPB && g < G4) {
        kv = ((const uint4*)keys)[g];
        pm = (kv.x >= thr ? 1u : 0u) | (kv.y >= thr ? 2u : 0u)
           | (kv.z >= thr ? 4u : 0u) | (kv.w >= thr ? 8u : 0u);
    }
    unsigned long long b0 = __ballot((pm & 1u) != 0u);
    unsigned long long b1 = __ballot((pm & 2u) != 0u);
    unsigned long long b2 = __ballot((pm & 4u) != 0u);
    unsigned long long b3 = __ballot((pm & 8u) != 0u);
    if (lane == 0)
        wcnt[wv] = __popcll(b0) + __popcll(b1) + __popcll(b2) + __popcll(b3);
    __syncthreads();
    if (t == 0) {
        int s = 0;
#pragma unroll
        for (int q = 0; q < 16; ++q) { wbase[q] = s; s += wcnt[q]; }
        s_base = s ? atomicAdd(cnt, s) : 0;
    }
    __syncthreads();
    if (pm) {
        unsigned long long lt = (lane == 0) ? 0ull : ((1ull << lane) - 1ull);
        int pos = s_base + wbase[wv]
                + __popcll(b0 & lt) + __popcll(b1 & lt) + __popcll(b2 & lt) + __popcll(b3 & lt);
        int n0 = g * 4;
        if (pm & 1u) { if (pos < CAP) cand[pos] = ((unsigned long long)kv.x << 32) | (unsigned)(~(unsigned)n0);       ++pos; }
        if (pm & 2u) { if (pos < CAP) cand[pos] = ((unsigned long long)kv.y << 32) | (unsigned)(~(unsigned)(n0 + 1)); ++pos; }
        if (pm & 4u) { if (pos < CAP) cand[pos] = ((unsigned long long)kv.z << 32) | (unsigned)(~(unsigned)(n0 + 2)); ++pos; }
        if (pm & 8u) { if (pos < CAP) cand[pos] = ((unsigned long long)kv.w << 32) | (unsigned)(~(unsigned)(n0 + 3)); ++pos; }
    }
}

// ============================================================================
// 3) rank select (R2 verbatim, proven)
// ============================================================================
__global__ void __launch_bounds__(1024)
rank_select_kernel(const unsigned long long* __restrict__ cand,
                   const int* __restrict__ cnt,
                   const float4* __restrict__ roi,
                   float4* __restrict__ sbox) {
    __shared__ unsigned long long s[CAP];
    __shared__ int red[1024];
    int tid = threadIdx.x;
    int c = cnt[0];
    if (c > CAP) c = CAP;
    for (int k = tid; k < CAP; k += 1024) s[k] = (k < c) ? cand[k] : 0ULL;
    __syncthreads();
    int e = tid & 63;
    int slice = tid >> 6;
    int i = blockIdx.x * 64 + e;
    unsigned long long v = (i < c) ? s[i] : 0ULL;
    int cnt_gt = 0;
    if (i < c) {
        int kbeg = slice * (CAP / 16);
        int kend = kbeg + (CAP / 16);
        if (kend > c) kend = c;
#pragma unroll 4
        for (int k = kbeg; k < kend; ++k)
            cnt_gt += (s[k] > v) ? 1 : 0;
    }
    red[tid] = cnt_gt;
    __syncthreads();
    if (slice == 0 && i < c) {
        int rank = 0;
#pragma unroll
        for (int q = 0; q < 16; ++q) rank += red[e + 64 * q];
        if (rank < M_TOP) {
            unsigned idx = ~((unsigned)v);
            sbox[rank] = roi[idx];
        }
    }
}

// ============================================================================
// 4) mask: 16 blocks x 256 thr, 1 word (64 IoUs) per thread (R2 verbatim)
// ============================================================================
__global__ void __launch_bounds__(256)
mask_kernel(const float4* __restrict__ sbox,
            unsigned long long* __restrict__ mask) {
    __shared__ float4 sb[SB_SZ];
    int tid = threadIdx.x;
#pragma unroll
    for (int q = 0; q < M_L / 256; ++q) {
        int j = tid + q * 256;
        sb[SIDX(j)] = sbox[j];
    }
    __syncthreads();
    int wid = blockIdx.x * 256 + tid;
    int i = wid >> 3;
    int w = wid & 7;
    unsigned long long bits = 0;
    int j0 = w << 6;
    if (j0 + 63 > i) {
        float4 bi = sb[SIDX(i)];
        float ai = (bi.z - bi.x) * (bi.w - bi.y);
        for (int b = 0; b < 64; ++b) {
            int j = j0 + b;
            if (j > i) {
                float4 bj = sb[SIDX(j)];
                float xx1 = fmaxf(bi.x, bj.x);
                float yy1 = fmaxf(bi.y, bj.y);
                float xx2 = fminf(bi.z, bj.z);
                float yy2 = fminf(bi.w, bj.w);
                float ww = fmaxf(xx2 - xx1, 0.0f);
                float hh = fmaxf(yy2 - yy1, 0.0f);
                float inter = ww * hh;
                float aj = (bj.z - bj.x) * (bj.w - bj.y);
                float uni = ai + aj - inter;
                float iou = inter / fmaxf(uni, 1e-12f);
                if (iou > IOU_THR) bits |= 1ull << b;
            }
        }
    }
    mask[wid] = bits;
}

__device__ __forceinline__ unsigned long long readlane64(unsigned long long v, int sl) {
    unsigned lo = (unsigned)__builtin_amdgcn_readlane((int)(unsigned)v, sl);
    unsigned hi = (unsigned)__builtin_amdgcn_readlane((int)(unsigned)(v >> 32), sl);
    return ((unsigned long long)hi << 32) | lo;
}

__device__ __forceinline__ unsigned long long shflxor64(unsigned long long v, int m) {
    unsigned lo = (unsigned)__shfl_xor((int)(unsigned)v, m);
    unsigned hi = (unsigned)__shfl_xor((int)(unsigned)(v >> 32), m);
    return ((unsigned long long)hi << 32) | lo;
}

// lane-distributed 64x64 bit-matrix transpose: in x[lane]=row(lane); out col(lane)
__device__ __forceinline__ unsigned long long bittranspose64(unsigned long long x, int lane) {
#pragma unroll
    for (int s = 0; s < 6; ++s) {
        const int j = 32 >> s;
        const unsigned long long lm =
            (j == 32) ? 0x00000000FFFFFFFFull :
            (j == 16) ? 0x0000FFFF0000FFFFull :
            (j ==  8) ? 0x00FF00FF00FF00FFull :
            (j ==  4) ? 0x0F0F0F0F0F0F0F0Full :
            (j ==  2) ? 0x3333333333333333ull :
                        0x5555555555555555ull;
        const unsigned long long hm = ~lm;
        unsigned long long y = shflxor64(x, j);
        x = (lane & j) ? ((x & hm) | ((y >> j) & lm))
                       : ((x & lm) | ((y << j) & hm));
    }
    return x;
}

// ============================================================================
// 5) walk: PARALLEL-PEEL greedy NMS. Per 64-box chunk: transpose the diagonal
//    block, then peel rounds {roots = live boxes with no live suppressor;
//    keep all roots; remove their suppressions} — exactly equivalent to the
//    sequential greedy order (lowest live bit is always a root). Kept indices
//    emitted per chunk in bit (=score) order; K_POST cap truncates the final
//    chunk's batch. Cross-chunk fold machinery unchanged (proven).
// ============================================================================
__global__ void __launch_bounds__(256)
walk_kernel(const unsigned long long* __restrict__ mask,
            const float4* __restrict__ sbox,
            const int* __restrict__ cnt,
            float4* __restrict__ out) {
    __shared__ unsigned long long lmask[M_L * NW_L];   // 32 KB
    __shared__ int s_keep[K_POST];
    __shared__ int s_kc;
    const int tid = threadIdx.x;

    {   // cooperative preload: 2048 uint4, 8 per thread
        const uint4* src = (const uint4*)mask;
        uint4* dst = (uint4*)lmask;
#pragma unroll
        for (int q = 0; q < (M_L * NW_L) / 2 / 256; ++q)
            dst[tid + q * 256] = src[tid + q * 256];
    }
    __syncthreads();

    if (tid < 64) {
        const int lane = tid;
        int c_eff = cnt[0];
        if (c_eff > M_TOP) c_eff = M_TOP;

        unsigned long long diag[NW_L];
#pragma unroll
        for (int cc = 0; cc < NW_L; ++cc)
            diag[cc] = lmask[(((cc << 6) | lane) << 3) + cc];

        unsigned long long remw = 0;             // lane holds remv word (lane&7)
        const int w = lane & 7;
        const int kgrp = lane >> 3;
        int kc = 0;                              // uniform
        bool stop = false;
#pragma unroll
        for (int cc = 0; cc < NW_L; ++cc) {
            const int base = cc << 6;
            unsigned long long valid =
                (c_eff >= base + 64) ? ~0ull
              : ((c_eff <= base) ? 0ull : ((1ull << (c_eff - base)) - 1ull));
            unsigned long long live = valid & ~readlane64(remw, cc);
            const unsigned long long row = diag[cc];            // my row's diag word
            const unsigned long long col = bittranspose64(row, lane);  // my column
            unsigned long long keptbits = 0;

            // ---- peel rounds (few; lowest live bit always roots => progress) ----
            while (live) {
                bool isroot = ((live >> lane) & 1ull) && ((col & live) == 0ull);
                unsigned long long roots = __ballot(isroot);
                unsigned long long val = ((roots >> lane) & 1ull) ? row : 0ull;
                val |= shflxor64(val, 1);
                val |= shflxor64(val, 2);
                val |= shflxor64(val, 4);
                val |= shflxor64(val, 8);
                val |= shflxor64(val, 16);
                val |= shflxor64(val, 32);       // uniform OR of root rows
                keptbits |= roots;
                live &= ~(roots | val);
            }

            // ---- emit kept indices in bit order; cap at K_POST ----
            int nk = __popcll(keptbits);
            int use = nk;
            if (kc + nk >= K_POST) { use = K_POST - kc; stop = true; }
            {
                unsigned long long tmp = keptbits;
                for (int p = 0; p < lane; ++p) tmp &= tmp - 1;   // lane-th set bit
                int mypos = __ffsll((unsigned long long)tmp) - 1;
                if (lane < use) s_keep[kc + lane] = base + mypos;
            }
            kc += use;
            if (stop) break;
            if (cc == NW_L - 1) break;

            // ---- fold: suppress future chunks with kept rows (proven) ----
            if (keptbits) {
                int mypos = 0;
                if (lane < nk) {
                    unsigned long long tmp = keptbits;
                    for (int p = 0; p < lane; ++p) tmp &= tmp - 1;
                    mypos = base + (__ffsll((unsigned long long)tmp) - 1);
                }
                unsigned long long acc = 0;
#pragma unroll
                for (int r = 0; r < 8; ++r) {    // covers up to 64 kept rows/chunk
                    int kg = (r << 3) | kgrp;
                    int rowid = __shfl(mypos, kg);
                    unsigned long long vv = (kg < nk) ? lmask[(rowid << 3) + w] : 0ull;
                    acc |= vv;
                }
                acc |= __shfl_xor(acc, 8);
                acc |= __shfl_xor(acc, 16);
                acc |= __shfl_xor(acc, 32);
                remw |= acc;
            }
        }
        // cold fallback: rows [M_L, c_eff) vs kept set (correctness only)
        if (!stop) {
            for (int i = M_L; i < c_eff && kc < K_POST; ++i) {
                float4 bi = sbox[i];
                float ai = (bi.z - bi.x) * (bi.w - bi.y);
                bool any = false;
                for (int k = lane; k < kc; k += 64) {
                    float4 bk = sbox[s_keep[k]];
                    float xx1 = fmaxf(bi.x, bk.x);
                    float yy1 = fmaxf(bi.y, bk.y);
                    float xx2 = fminf(bi.z, bk.z);
                    float yy2 = fminf(bi.w, bk.w);
                    float ww = fmaxf(xx2 - xx1, 0.0f);
                    float hh = fmaxf(yy2 - yy1, 0.0f);
                    float inter = ww * hh;
                    float ak = (bk.z - bk.x) * (bk.w - bk.y);
                    float uni = ai + ak - inter;
                    if (inter / fmaxf(uni, 1e-12f) > IOU_THR) any = true;
                }
                if (__ballot(any) == 0ull) {
                    if (lane == 0) s_keep[kc] = i;
                    ++kc;
                }
            }
        }
        if (lane == 0) s_kc = kc;
    }
    __syncthreads();
    int kcf = s_kc;
    for (int j = tid; j < K_POST; j += 256)
        out[j] = (j < kcf) ? sbox[s_keep[j]] : make_float4(0.f, 0.f, 0.f, 0.f);
}

extern "C" void kernel_launch(void* const* d_in, const int* in_sizes, int n_in,
                              void* d_out, int out_size, void* d_ws, size_t ws_size,
                              hipStream_t stream) {
    const float2* cls = (const float2*)d_in[0];   // (1,100,100,18) fp32 -> logit pairs
    const float4* reg = (const float4*)d_in[1];   // (1,90000,4)
    const float4* anc = (const float4*)d_in[2];   // (90000,4)
    float4* out = (float4*)d_out;                 // 300 x 4 fp32

    char* ws = (char*)d_ws;
    int*                cnt  = (int*)(ws + OFF_CNT);
    unsigned short*     hist = (unsigned short*)(ws + OFF_HIST);
    float4*             roi  = (float4*)(ws + OFF_ROI);
    unsigned*           keys = (unsigned*)(ws + OFF_KEYS);
    unsigned long long* cand = (unsigned long long*)(ws + OFF_CAND);
    float4*             sbox = (float4*)(ws + OFF_SBOX);
    unsigned long long* mask = (unsigned long long*)(ws + OFF_MASK);

    decode_kernel<<<NB_D, 512, 0, stream>>>(cls, reg, anc, roi, keys, hist, cnt);
    compact_kernel<<<NB_C, 1024, 0, stream>>>(keys, hist, cnt, cand);
    rank_select_kernel<<<CAP / 64, 1024, 0, stream>>>(cand, cnt, roi, sbox);
    mask_kernel<<<M_L * NW_L / 256, 256, 0, stream>>>(sbox, mask);
    walk_kernel<<<1, 256, 0, stream>>>(mask, sbox, cnt, out);
}

// Round 8
// 111.467 us; speedup vs baseline: 1.7156x; 1.0467x over previous
//
#include <hip/hip_runtime.h>
#include <stdint.h>

#pragma clang fp contract(off)

#define N_ANCH 90000
#define M_TOP  1024          // selection scope; walk fast path covers M_L=512
#define M_L    512           // mask/walk fast-path scope; stop row ~330 for this input
#define NW_L   8             // mask words per row (M_L/64)
#define K_POST 300
#define CAP    2048          // candidate capacity
#define WINB   0x3D00        // hist window base: p>=~0.031
#define WINSZ  768           // window bins [0x3D00, 0x4000) — all bins >= WINB
#define MIN_SIZE (16.0f / 800.0f)
#define IOU_THR  0.7f

#define NB_D   176           // decode blocks (x512 thr; 1 anchor/thread)
#define NB_C   32            // compact blocks (x1024 thr)
#define GPB    704           // uint4 key-groups per compact block: ceil(22500/32)
#define G4     (N_ANCH / 4)  // 22500

// sb[] bank-conflict swizzle
#define SIDX(j) ((j) + ((j) >> 6))
#define SB_SZ   (M_L + NW_L)

// ---- workspace layout (bytes); all regions written before read; no memset ----
#define OFF_CNT   0                          // int (zeroed by decode blk0)
#define OFF_HIST  64                         // u16[768*176] = 270336 -> 270400
#define OFF_ROI   270400                     // float4[90000] = 1440000 -> 1710400
#define OFF_KEYS  1710400                    // u32[90000] = 360000 -> 2070400
#define OFF_CAND  2070400                    // u64[2048] = 16384 -> 2086784
#define OFF_SBOX  2086784                    // float4[1024] = 16384 -> 2103168
#define OFF_MASK  2103168                    // u64[4096] = 32768 -> 2135936

// ============================================================================
// 1) decode: 176 blocks x 512, one anchor/thread (proven). Writes roi, keys,
//    transposed u16 hist hist[bin*176 + bid]; blk0 zeroes cnt.
// ============================================================================
__global__ void __launch_bounds__(512)
decode_kernel(const float2* __restrict__ cls,
              const float4* __restrict__ reg,
              const float4* __restrict__ anc,
              float4* __restrict__ roi,
              unsigned* __restrict__ keys,
              unsigned short* __restrict__ hist,
              int* __restrict__ cnt) {
    __shared__ int lh[WINSZ];
    const int tid = threadIdx.x;
    const int bid = blockIdx.x;
    for (int k = tid; k < WINSZ; k += 512) lh[k] = 0;
    if (bid == 0 && tid == 0) cnt[0] = 0;
    __syncthreads();

    const int n = bid * 512 + tid;
    if (n < N_ANCH) {
        float4 a = anc[n];
        float4 r = reg[n];
        float aw  = a.z - a.x;
        float ah  = a.w - a.y;
        float acx = (a.z + a.x) * 0.5f;
        float acy = (a.w + a.y) * 0.5f;
        float cx = r.x * aw + acx;
        float cy = r.y * ah + acy;
        float w  = expf(r.z) * aw;
        float h  = expf(r.w) * ah;
        float x1 = fminf(fmaxf(cx - w * 0.5f, 0.0f), 1.0f);
        float y1 = fminf(fmaxf(cy - h * 0.5f, 0.0f), 1.0f);
        float x2 = fminf(fmaxf(cx + w * 0.5f, 0.0f), 1.0f);
        float y2 = fminf(fmaxf(cy + h * 0.5f, 0.0f), 1.0f);
        roi[n] = make_float4(x1, y1, x2, y2);

        float2 c = cls[n];
        float m  = fmaxf(c.x, c.y);
        float e0 = expf(c.x - m);
        float e1 = expf(c.y - m);
        float p  = e1 / (e0 + e1);

        bool ok = ((x2 - x1) >= MIN_SIZE) && ((y2 - y1) >= MIN_SIZE);
        unsigned key = ok ? (__float_as_uint(p) ^ 0x80000000u) : 0u;  // monotone; invalid -> 0
        keys[n] = key;
        if (key != 0u) {
            int hb = (int)(key >> 16) - 0x8000;
            if (hb >= WINB) atomicAdd(&lh[hb - WINB], 1);
        }
    }
    __syncthreads();
    for (int k = tid; k < WINSZ; k += 512)
        hist[k * NB_D + bid] = (unsigned short)lh[k];   // count <= 512 fits u16
}

// ============================================================================
// 2) compact: 32 blocks x 1024 (proven): shfl-scan threshold + slice compact
//    via ballot + one global atomicAdd per block.
// ============================================================================
__global__ void __launch_bounds__(1024)
compact_kernel(const unsigned* __restrict__ keys,
               const unsigned short* __restrict__ hist,
               int* __restrict__ cnt,
               unsigned long long* __restrict__ cand) {
    __shared__ int s_w[16];
    __shared__ unsigned s_thr;
    __shared__ int wcnt[16], wbase[16], s_base;
    const int t = threadIdx.x;
    const int bid = blockIdx.x;
    const int lane = t & 63, wv = t >> 6;

    int own = 0;
    if (t < WINSZ) {
        const uint4* hp = (const uint4*)(hist + (WINSZ - 1 - t) * NB_D);
#pragma unroll
        for (int q = 0; q < NB_D / 8; ++q) {
            uint4 u = hp[q];
            own += (int)((u.x & 0xffffu) + (u.x >> 16) + (u.y & 0xffffu) + (u.y >> 16)
                       + (u.z & 0xffffu) + (u.z >> 16) + (u.w & 0xffffu) + (u.w >> 16));
        }
    }
    int x = own;
#pragma unroll
    for (int d = 1; d < 64; d <<= 1) { int y = __shfl_up(x, d); if (lane >= d) x += y; }
    if (lane == 63) s_w[wv] = x;
    __syncthreads();
    int incl = x;
#pragma unroll
    for (int q = 0; q < 16; ++q) if (q < wv) incl += s_w[q];
    if (t < WINSZ && incl >= M_TOP && (incl - own) < M_TOP)
        s_thr = ((unsigned)(0x8000 + WINB + (WINSZ - 1 - t))) << 16;
    if (t == 1023 && incl < M_TOP)
        s_thr = 0x80000000u;
    __syncthreads();
    const unsigned thr = s_thr;

    unsigned pm = 0;
    uint4 kv = make_uint4(0u, 0u, 0u, 0u);
    const int g = bid * GPB + t;
    if (t < GPB && g < G4) {
        kv = ((const uint4*)keys)[g];
        pm = (kv.x >= thr ? 1u : 0u) | (kv.y >= thr ? 2u : 0u)
           | (kv.z >= thr ? 4u : 0u) | (kv.w >= thr ? 8u : 0u);
    }
    unsigned long long b0 = __ballot((pm & 1u) != 0u);
    unsigned long long b1 = __ballot((pm & 2u) != 0u);
    unsigned long long b2 = __ballot((pm & 4u) != 0u);
    unsigned long long b3 = __ballot((pm & 8u) != 0u);
    if (lane == 0)
        wcnt[wv] = __popcll(b0) + __popcll(b1) + __popcll(b2) + __popcll(b3);
    __syncthreads();
    if (t == 0) {
        int s = 0;
#pragma unroll
        for (int q = 0; q < 16; ++q) { wbase[q] = s; s += wcnt[q]; }
        s_base = s ? atomicAdd(cnt, s) : 0;
    }
    __syncthreads();
    if (pm) {
        unsigned long long lt = (lane == 0) ? 0ull : ((1ull << lane) - 1ull);
        int pos = s_base + wbase[wv]
                + __popcll(b0 & lt) + __popcll(b1 & lt) + __popcll(b2 & lt) + __popcll(b3 & lt);
        int n0 = g * 4;
        if (pm & 1u) { if (pos < CAP) cand[pos] = ((unsigned long long)kv.x << 32) | (unsigned)(~(unsigned)n0);       ++pos; }
        if (pm & 2u) { if (pos < CAP) cand[pos] = ((unsigned long long)kv.y << 32) | (unsigned)(~(unsigned)(n0 + 1)); ++pos; }
        if (pm & 4u) { if (pos < CAP) cand[pos] = ((unsigned long long)kv.z << 32) | (unsigned)(~(unsigned)(n0 + 2)); ++pos; }
        if (pm & 8u) { if (pos < CAP) cand[pos] = ((unsigned long long)kv.w << 32) | (unsigned)(~(unsigned)(n0 + 3)); ++pos; }
    }
}

// ============================================================================
// 3) rank select (proven)
// ============================================================================
__global__ void __launch_bounds__(1024)
rank_select_kernel(const unsigned long long* __restrict__ cand,
                   const int* __restrict__ cnt,
                   const float4* __restrict__ roi,
                   float4* __restrict__ sbox) {
    __shared__ unsigned long long s[CAP];
    __shared__ int red[1024];
    int tid = threadIdx.x;
    int c = cnt[0];
    if (c > CAP) c = CAP;
    for (int k = tid; k < CAP; k += 1024) s[k] = (k < c) ? cand[k] : 0ULL;
    __syncthreads();
    int e = tid & 63;
    int slice = tid >> 6;
    int i = blockIdx.x * 64 + e;
    unsigned long long v = (i < c) ? s[i] : 0ULL;
    int cnt_gt = 0;
    if (i < c) {
        int kbeg = slice * (CAP / 16);
        int kend = kbeg + (CAP / 16);
        if (kend > c) kend = c;
#pragma unroll 4
        for (int k = kbeg; k < kend; ++k)
            cnt_gt += (s[k] > v) ? 1 : 0;
    }
    red[tid] = cnt_gt;
    __syncthreads();
    if (slice == 0 && i < c) {
        int rank = 0;
#pragma unroll
        for (int q = 0; q < 16; ++q) rank += red[e + 64 * q];
        if (rank < M_TOP) {
            unsigned idx = ~((unsigned)v);
            sbox[rank] = roi[idx];
        }
    }
}

// ============================================================================
// 4) mask: 64 blocks x 64 thr, 1 word (64 IoUs) per thread. 1 wave/block on
//    64 CUs -> 4x less per-CU work than the 16-block version. Preload 8
//    float4/thread (swizzled scatter).
// ============================================================================
__global__ void __launch_bounds__(64)
mask_kernel(const float4* __restrict__ sbox,
            unsigned long long* __restrict__ mask) {
    __shared__ float4 sb[SB_SZ];
    int tid = threadIdx.x;
#pragma unroll
    for (int q = 0; q < M_L / 64; ++q) {      // 8 rows per thread
        int j = tid + q * 64;
        sb[SIDX(j)] = sbox[j];
    }
    __syncthreads();
    int wid = blockIdx.x * 64 + tid;          // [0, 4096)
    int i = wid >> 3;
    int w = wid & 7;
    unsigned long long bits = 0;
    int j0 = w << 6;
    if (j0 + 63 > i) {                        // skip words fully below diagonal
        float4 bi = sb[SIDX(i)];
        float ai = (bi.z - bi.x) * (bi.w - bi.y);
        for (int b = 0; b < 64; ++b) {
            int j = j0 + b;
            if (j > i) {
                float4 bj = sb[SIDX(j)];
                float xx1 = fmaxf(bi.x, bj.x);
                float yy1 = fmaxf(bi.y, bj.y);
                float xx2 = fminf(bi.z, bj.z);
                float yy2 = fminf(bi.w, bj.w);
                float ww = fmaxf(xx2 - xx1, 0.0f);
                float hh = fmaxf(yy2 - yy1, 0.0f);
                float inter = ww * hh;
                float aj = (bj.z - bj.x) * (bj.w - bj.y);
                float uni = ai + aj - inter;
                float iou = inter / fmaxf(uni, 1e-12f);
                if (iou > IOU_THR) bits |= 1ull << b;
            }
        }
    }
    mask[wid] = bits;
}

__device__ __forceinline__ unsigned long long readlane64(unsigned long long v, int sl) {
    unsigned lo = (unsigned)__builtin_amdgcn_readlane((int)(unsigned)v, sl);
    unsigned hi = (unsigned)__builtin_amdgcn_readlane((int)(unsigned)(v >> 32), sl);
    return ((unsigned long long)hi << 32) | lo;
}

__device__ __forceinline__ unsigned long long shflxor64(unsigned long long v, int m) {
    unsigned lo = (unsigned)__shfl_xor((int)(unsigned)v, m);
    unsigned hi = (unsigned)__shfl_xor((int)(unsigned)(v >> 32), m);
    return ((unsigned long long)hi << 32) | lo;
}

// lane-distributed 64x64 bit-matrix transpose: in x[lane]=row(lane); out col(lane)
__device__ __forceinline__ unsigned long long bittranspose64(unsigned long long x, int lane) {
#pragma unroll
    for (int s = 0; s < 6; ++s) {
        const int j = 32 >> s;
        const unsigned long long lm =
            (j == 32) ? 0x00000000FFFFFFFFull :
            (j == 16) ? 0x0000FFFF0000FFFFull :
            (j ==  8) ? 0x00FF00FF00FF00FFull :
            (j ==  4) ? 0x0F0F0F0F0F0F0F0Full :
            (j ==  2) ? 0x3333333333333333ull :
                        0x5555555555555555ull;
        const unsigned long long hm = ~lm;
        unsigned long long y = shflxor64(x, j);
        x = (lane & j) ? ((x & hm) | ((y >> j) & lm))
                       : ((x & lm) | ((y << j) & hm));
    }
    return x;
}

// ============================================================================
// 5) walk: parallel-peel greedy NMS (proven R7; exactly order-equivalent to
//    the sequential greedy).
// ============================================================================
__global__ void __launch_bounds__(256)
walk_kernel(const unsigned long long* __restrict__ mask,
            const float4* __restrict__ sbox,
            const int* __restrict__ cnt,
            float4* __restrict__ out) {
    __shared__ unsigned long long lmask[M_L * NW_L];   // 32 KB
    __shared__ int s_keep[K_POST];
    __shared__ int s_kc;
    const int tid = threadIdx.x;

    {   // cooperative preload: 2048 uint4, 8 per thread
        const uint4* src = (const uint4*)mask;
        uint4* dst = (uint4*)lmask;
#pragma unroll
        for (int q = 0; q < (M_L * NW_L) / 2 / 256; ++q)
            dst[tid + q * 256] = src[tid + q * 256];
    }
    __syncthreads();

    if (tid < 64) {
        const int lane = tid;
        int c_eff = cnt[0];
        if (c_eff > M_TOP) c_eff = M_TOP;

        unsigned long long diag[NW_L];
#pragma unroll
        for (int cc = 0; cc < NW_L; ++cc)
            diag[cc] = lmask[(((cc << 6) | lane) << 3) + cc];

        unsigned long long remw = 0;             // lane holds remv word (lane&7)
        const int w = lane & 7;
        const int kgrp = lane >> 3;
        int kc = 0;                              // uniform
        bool stop = false;
#pragma unroll
        for (int cc = 0; cc < NW_L; ++cc) {
            const int base = cc << 6;
            unsigned long long valid =
                (c_eff >= base + 64) ? ~0ull
              : ((c_eff <= base) ? 0ull : ((1ull << (c_eff - base)) - 1ull));
            unsigned long long live = valid & ~readlane64(remw, cc);
            const unsigned long long row = diag[cc];            // my row's diag word
            const unsigned long long col = bittranspose64(row, lane);  // my column
            unsigned long long keptbits = 0;

            // ---- peel rounds (few; lowest live bit always roots => progress) ----
            while (live) {
                bool isroot = ((live >> lane) & 1ull) && ((col & live) == 0ull);
                unsigned long long roots = __ballot(isroot);
                unsigned long long val = ((roots >> lane) & 1ull) ? row : 0ull;
                val |= shflxor64(val, 1);
                val |= shflxor64(val, 2);
                val |= shflxor64(val, 4);
                val |= shflxor64(val, 8);
                val |= shflxor64(val, 16);
                val |= shflxor64(val, 32);       // uniform OR of root rows
                keptbits |= roots;
                live &= ~(roots | val);
            }

            // ---- emit kept indices in bit order; cap at K_POST ----
            int nk = __popcll(keptbits);
            int use = nk;
            if (kc + nk >= K_POST) { use = K_POST - kc; stop = true; }
            {
                unsigned long long tmp = keptbits;
                for (int p = 0; p < lane; ++p) tmp &= tmp - 1;   // lane-th set bit
                int mypos = __ffsll((unsigned long long)tmp) - 1;
                if (lane < use) s_keep[kc + lane] = base + mypos;
            }
            kc += use;
            if (stop) break;
            if (cc == NW_L - 1) break;

            // ---- fold: suppress future chunks with kept rows (proven) ----
            if (keptbits) {
                int mypos = 0;
                if (lane < nk) {
                    unsigned long long tmp = keptbits;
                    for (int p = 0; p < lane; ++p) tmp &= tmp - 1;
                    mypos = base + (__ffsll((unsigned long long)tmp) - 1);
                }
                unsigned long long acc = 0;
#pragma unroll
                for (int r = 0; r < 8; ++r) {    // covers up to 64 kept rows/chunk
                    int kg = (r << 3) | kgrp;
                    int rowid = __shfl(mypos, kg);
                    unsigned long long vv = (kg < nk) ? lmask[(rowid << 3) + w] : 0ull;
                    acc |= vv;
                }
                acc |= __shfl_xor(acc, 8);
                acc |= __shfl_xor(acc, 16);
                acc |= __shfl_xor(acc, 32);
                remw |= acc;
            }
        }
        // cold fallback: rows [M_L, c_eff) vs kept set (correctness only)
        if (!stop) {
            for (int i = M_L; i < c_eff && kc < K_POST; ++i) {
                float4 bi = sbox[i];
                float ai = (bi.z - bi.x) * (bi.w - bi.y);
                bool any = false;
                for (int k = lane; k < kc; k += 64) {
                    float4 bk = sbox[s_keep[k]];
                    float xx1 = fmaxf(bi.x, bk.x);
                    float yy1 = fmaxf(bi.y, bk.y);
                    float xx2 = fminf(bi.z, bk.z);
                    float yy2 = fminf(bi.w, bk.w);
                    float ww = fmaxf(xx2 - xx1, 0.0f);
                    float hh = fmaxf(yy2 - yy1, 0.0f);
                    float inter = ww * hh;
                    float ak = (bk.z - bk.x) * (bk.w - bk.y);
                    float uni = ai + ak - inter;
                    if (inter / fmaxf(uni, 1e-12f) > IOU_THR) any = true;
                }
                if (__ballot(any) == 0ull) {
                    if (lane == 0) s_keep[kc] = i;
                    ++kc;
                }
            }
        }
        if (lane == 0) s_kc = kc;
    }
    __syncthreads();
    int kcf = s_kc;
    for (int j = tid; j < K_POST; j += 256)
        out[j] = (j < kcf) ? sbox[s_keep[j]] : make_float4(0.f, 0.f, 0.f, 0.f);
}

extern "C" void kernel_launch(void* const* d_in, const int* in_sizes, int n_in,
                              void* d_out, int out_size, void* d_ws, size_t ws_size,
                              hipStream_t stream) {
    const float2* cls = (const float2*)d_in[0];   // (1,100,100,18) fp32 -> logit pairs
    const float4* reg = (const float4*)d_in[1];   // (1,90000,4)
    const float4* anc = (const float4*)d_in[2];   // (90000,4)
    float4* out = (float4*)d_out;                 // 300 x 4 fp32

    char* ws = (char*)d_ws;
    int*                cnt  = (int*)(ws + OFF_CNT);
    unsigned short*     hist = (unsigned short*)(ws + OFF_HIST);
    float4*             roi  = (float4*)(ws + OFF_ROI);
    unsigned*           keys = (unsigned*)(ws + OFF_KEYS);
    unsigned long long* cand = (unsigned long long*)(ws + OFF_CAND);
    float4*             sbox = (float4*)(ws + OFF_SBOX);
    unsigned long long* mask = (unsigned long long*)(ws + OFF_MASK);

    decode_kernel<<<NB_D, 512, 0, stream>>>(cls, reg, anc, roi, keys, hist, cnt);
    compact_kernel<<<NB_C, 1024, 0, stream>>>(keys, hist, cnt, cand);
    rank_select_kernel<<<CAP / 64, 1024, 0, stream>>>(cand, cnt, roi, sbox);
    mask_kernel<<<M_L * NW_L / 64, 64, 0, stream>>>(sbox, mask);
    walk_kernel<<<1, 256, 0, stream>>>(mask, sbox, cnt, out);
}